// Round 7
// baseline (502.711 us; speedup 1.0000x reference)
//
#include <hip/hip_runtime.h>
#include <math.h>

// Problem dims (fixed by reference)
#define B_   4
#define L_   1024
#define D_   512
#define CHI_ 32
#define S_   4
#define BT_  (B_ * L_)          // 4096 rows
#define NC_  2560               // fused GEMM width: 1024 AbarI | 1024 G | 512 gate

// ---------------------------------------------------------------------------
// Cross-lane helpers
// ---------------------------------------------------------------------------
__device__ __forceinline__ float readlane_f(float v, int l) {
    return __int_as_float(__builtin_amdgcn_readlane(__float_as_int(v), l));
}

__device__ __forceinline__ float bpermute_f(int byte_idx, float v) {
    return __int_as_float(__builtin_amdgcn_ds_bpermute(byte_idx, __float_as_int(v)));
}

template <int CTRL>
__device__ __forceinline__ float dpp_add(float x) {
    int y = __builtin_amdgcn_update_dpp(0, __float_as_int(x), CTRL, 0xf, 0xf, true);
    return x + __int_as_float(y);
}

// Sum of lanes 0..31, valid in lane 31 (row_shr moves toward HIGHER lanes).
__device__ __forceinline__ float reduce32_to_lane31(float x) {
    x = dpp_add<0x111>(x);
    x = dpp_add<0x112>(x);
    x = dpp_add<0x114>(x);
    x = dpp_add<0x118>(x);
    x = dpp_add<0x142>(x);  // row_bcast15 -> lane31
    return x;
}

// Octet sum; complete sum lands in the TOP lane of each octet ((lane&7)==7).
__device__ __forceinline__ float octet_sum(float x) {
    x = dpp_add<0x111>(x);
    x = dpp_add<0x112>(x);
    x = dpp_add<0x114>(x);
    return x;
}

// ---------------------------------------------------------------------------
// Async global->LDS DMA (HW writes to wave-uniform LDS base + lane*size).
// ---------------------------------------------------------------------------
__device__ __forceinline__ void dma16(const float* g, float* l) {
    __builtin_amdgcn_global_load_lds(
        (const __attribute__((address_space(1))) float*)g,
        (__attribute__((address_space(3))) float*)l, 16, 0, 0);
}
__device__ __forceinline__ void dma4(const float* g, float* l) {
    __builtin_amdgcn_global_load_lds(
        (const __attribute__((address_space(1))) float*)g,
        (__attribute__((address_space(3))) float*)l, 4, 0, 0);
}

__device__ __forceinline__ unsigned lds_off(const void* p) {
    return (unsigned)(unsigned long long)
        (const __attribute__((address_space(3))) void*)p;
}

// ---------------------------------------------------------------------------
// buildW: fold W_site with (sum_p) and W_bridge; append W_gate. (unchanged R5)
// ---------------------------------------------------------------------------
__global__ __launch_bounds__(256) void buildW_kernel(
    const float* __restrict__ Ws, const float* __restrict__ bs,
    const float* __restrict__ Wb, const float* __restrict__ Wg,
    const float* __restrict__ bg, float* __restrict__ Wcomb,
    float* __restrict__ biasC)
{
    const int tid = threadIdx.x;

    if (blockIdx.x == 512) {   // bias block
        for (int f = tid; f < NC_; f += 256) {
            float acc;
            if (f < 1024) {
                const int q = f >> 8, rem = f & 255, i = rem >> 2, e = rem & 3;
                const int l = 4 * (i & 7) + e, r = (i >> 3) + 8 * q;
                const float* p = bs + l * 128 + r;
                acc = p[0] + p[32] + p[64] + p[96];
            } else if (f < 2048) {
                const int g = f - 1024, l = g >> 5, j = g & 31;
                acc = 0.f;
                for (int pr = 0; pr < 128; ++pr)
                    acc = fmaf(bs[l * 128 + pr], Wb[pr * 32 + j], acc);
            } else {
                acc = bg[f - 2048];
            }
            biasC[f] = acc;
        }
        return;
    }

    __shared__ float wsrow[4096];
    __shared__ float wbs[4096];

    const int d = blockIdx.x;
    #pragma unroll
    for (int i = 0; i < 16; ++i) {
        wsrow[i * 256 + tid] = Ws[(size_t)d * 4096 + i * 256 + tid];
        wbs[i * 256 + tid]   = Wb[i * 256 + tid];
    }
    __syncthreads();

    float* wrow = Wcomb + (size_t)d * NC_;

    #pragma unroll
    for (int ii = 0; ii < 4; ++ii) {
        const int f = ii * 256 + tid;
        const int q = f >> 8, rem = f & 255, i = rem >> 2, e = rem & 3;
        const int l = 4 * (i & 7) + e, r = (i >> 3) + 8 * q;
        const float* p = wsrow + l * 128 + r;
        wrow[f] = p[0] + p[32] + p[64] + p[96];
    }
    #pragma unroll
    for (int ii = 0; ii < 4; ++ii) {
        const int g = ii * 256 + tid;
        const int l = g >> 5, j = g & 31;
        float acc = 0.f;
        #pragma unroll 8
        for (int pr = 0; pr < 128; ++pr)
            acc = fmaf(wsrow[l * 128 + pr], wbs[pr * 32 + j], acc);
        wrow[1024 + g] = acc;
    }
    #pragma unroll
    for (int ii = 0; ii < 2; ++ii) {
        const int c = ii * 256 + tid;
        wrow[2048 + c] = Wg[(size_t)d * 512 + c];
    }
}

// ---------------------------------------------------------------------------
// Generic fp32 GEMM with bias (unchanged R5)
// ---------------------------------------------------------------------------
__global__ __launch_bounds__(256) void gemm_bias_kernel(
    const float* __restrict__ A, const float* __restrict__ Bm,
    const float* __restrict__ bias, float* __restrict__ C,
    int M, int N, int K)
{
    __shared__ float As[32][68];
    __shared__ float Bs[32][64];

    const int tid = threadIdx.x;
    const int tx = tid & 15;
    const int ty = tid >> 4;
    const int m0 = blockIdx.y * 64;
    const int n0 = blockIdx.x * 64;

    float c[4][4] = {};

    for (int k0 = 0; k0 < K; k0 += 32) {
        {
            const int o = tid * 8;
            const int m = o >> 5;
            const int k = o & 31;
            const float* ap = A + (size_t)(m0 + m) * K + k0 + k;
            const float4 a0 = *(const float4*)ap;
            const float4 a1 = *(const float4*)(ap + 4);
            As[k + 0][m] = a0.x; As[k + 1][m] = a0.y;
            As[k + 2][m] = a0.z; As[k + 3][m] = a0.w;
            As[k + 4][m] = a1.x; As[k + 5][m] = a1.y;
            As[k + 6][m] = a1.z; As[k + 7][m] = a1.w;
        }
        {
            const int o = tid * 8;
            const int k = o >> 6;
            const int n = o & 63;
            const float* bp = Bm + (size_t)(k0 + k) * N + n0 + n;
            *(float4*)&Bs[k][n]     = *(const float4*)bp;
            *(float4*)&Bs[k][n + 4] = *(const float4*)(bp + 4);
        }
        __syncthreads();

        #pragma unroll
        for (int kk = 0; kk < 32; ++kk) {
            const float4 av = *(const float4*)&As[kk][ty * 4];
            const float4 bv = *(const float4*)&Bs[kk][tx * 4];
            const float a[4] = {av.x, av.y, av.z, av.w};
            const float b[4] = {bv.x, bv.y, bv.z, bv.w};
            #pragma unroll
            for (int i = 0; i < 4; ++i)
                #pragma unroll
                for (int j = 0; j < 4; ++j)
                    c[i][j] = fmaf(a[i], b[j], c[i][j]);
        }
        __syncthreads();
    }

    const float4 bv = *(const float4*)&bias[n0 + tx * 4];
    #pragma unroll
    for (int i = 0; i < 4; ++i) {
        float4 outv;
        outv.x = c[i][0] + bv.x;
        outv.y = c[i][1] + bv.y;
        outv.z = c[i][2] + bv.z;
        outv.w = c[i][3] + bv.w;
        *(float4*)&C[(size_t)(m0 + ty * 4 + i) * N + n0 + tx * 4] = outv;
    }
}

// ---------------------------------------------------------------------------
// cvec: c[bt][r] = sum_l u[l]*Abar[l][r]  (unchanged R5)
// ---------------------------------------------------------------------------
__global__ __launch_bounds__(256) void cvec_kernel(
    const float* __restrict__ Cc, const float* __restrict__ x,
    float* __restrict__ cBuf)
{
    const int tid  = threadIdx.x;
    const int lane = tid & 63;
    const int bt   = blockIdx.x * 4 + (tid >> 6);

    const float* base = Cc + (size_t)bt * NC_ + 4 * lane;
    float4 a0 = *(const float4*)(base + 0);
    float4 a1 = *(const float4*)(base + 256);
    float4 a2 = *(const float4*)(base + 512);
    float4 a3 = *(const float4*)(base + 768);

    const float u = x[(size_t)bt * D_ + (lane & 31)];
    const int idx0 = 16 * (lane & 7);
    const float u0 = bpermute_f(idx0 + 0,  u);
    const float u1 = bpermute_f(idx0 + 4,  u);
    const float u2 = bpermute_f(idx0 + 8,  u);
    const float u3 = bpermute_f(idx0 + 12, u);

    float p0 = fmaf(u3, a0.w, fmaf(u2, a0.z, fmaf(u1, a0.y, u0 * a0.x)));
    float p1 = fmaf(u3, a1.w, fmaf(u2, a1.z, fmaf(u1, a1.y, u0 * a1.x)));
    float p2 = fmaf(u3, a2.w, fmaf(u2, a2.z, fmaf(u1, a2.y, u0 * a2.x)));
    float p3 = fmaf(u3, a3.w, fmaf(u2, a3.z, fmaf(u1, a3.y, u0 * a3.x)));

    p0 = octet_sum(p0); p1 = octet_sum(p1);
    p2 = octet_sum(p2); p3 = octet_sum(p3);

    if ((lane & 7) == 7) {
        const int k = lane >> 3;
        float* cp = cBuf + (size_t)bt * 32 + k;
        cp[0]  = p0;
        cp[8]  = p1;
        cp[16] = p2;
        cp[24] = p3;
    }
}

// ---------------------------------------------------------------------------
// Serial scan, LDS ring fed by global_load_lds with hand-placed waits.
// Single stage, complete-at-blob-exit discipline (no tied asm operands):
//   iter n (slot j=n&7):
//     norm DPP + blob W (4 bpermute broadcasts, no wait)
//     blob R: s_waitcnt vmcnt(35); 5 ds_read slot j; s_waitcnt lgkmcnt(0)
//             (drains its reads AND blob W's bpermutes -> outputs final)
//     store w_n; DMA row n+8 -> slot j (safe: reads drained)
//     fma/octet; blob D: 4 redistribute bpermutes + lgkmcnt(0); select; fma.
// vm accounting: prologue = 8 pure DMA groups (40 ops); loop = 1 store +
// 5 DMA per iter, all AFTER the blob. Newer-than-group-n ops at blob R:
// 35 at iter 0 (exact), 42 steady (vmcnt(35) over-waits 7 long-done ops).
// All lgkm ops live inside asm so the compiler's waitcnt pass never sees
// them next to the LDS-DMA ops (no conservative vmcnt(0) insertion).
// ---------------------------------------------------------------------------
__global__ __launch_bounds__(64, 1) void scan_kernel(
    const float* __restrict__ Cc, const float* __restrict__ cBuf,
    float* __restrict__ wOut)
{
    __shared__ __align__(16) float slots[8][1088];   // 4096B row + c + pad

    const int b   = blockIdx.x;
    const int tid = threadIdx.x;

    const float* Crow = Cc + (size_t)b * L_ * NC_;
    const float* cb   = cBuf + (size_t)b * L_ * 32;
    float*       wo   = wOut + (size_t)b * L_ * 64 + tid;

    const int laneC = tid & 31;
    const unsigned rowAddr = lds_off(&slots[0][0]) + 16u * (unsigned)tid;
    const unsigned cAddr   = lds_off(&slots[0][0]) + 4096u + 4u * (unsigned)tid;

    // broadcast byte-indices: wb_e = w[4*(tid&7)+e]
    const int ia0 = 16 * (tid & 7) + 0;
    const int ia1 = 16 * (tid & 7) + 4;
    const int ia2 = 16 * (tid & 7) + 8;
    const int ia3 = 16 * (tid & 7) + 12;
    // redistribute: octet sum lives in octet TOP lane 8*(tid&7)+7
    const int idxRv = 32 * (tid & 7) + 28;
    const bool selA = (tid >> 3) & 1;
    const bool selB = (tid >> 4) & 1;

    // ---- prologue: 8 DMA groups (rows 0..7), 40 vm ops, no stores ----
    #pragma unroll
    for (int k = 0; k < 8; ++k) {
        const float* rp = Crow + (size_t)k * NC_;
        #pragma unroll
        for (int q = 0; q < 4; ++q)
            dma16(rp + 256 * q + 4 * tid, &slots[k][256 * q]);
        dma4(cb + k * 32 + laneC, &slots[k][1024]);
    }

    float w = 0.f;   // w_0 = 0 (h_0 = 0)

    for (int t = 0; t < L_; t += 8) {
        #pragma unroll
        for (int j = 0; j < 8; ++j) {
            const int n = t + j;

            // ---- norm chain (VALU, independent of LDS stage) ----
            float red = reduce32_to_lane31(w * w);

            // ---- blob W: broadcasts of w (latency overlaps blob R drain) ----
            float wb0, wb1, wb2, wb3;
            asm volatile(
                "ds_bpermute_b32 %0, %4, %8\n\t"
                "ds_bpermute_b32 %1, %5, %8\n\t"
                "ds_bpermute_b32 %2, %6, %8\n\t"
                "ds_bpermute_b32 %3, %7, %8"
                : "=&v"(wb0), "=&v"(wb1), "=&v"(wb2), "=&v"(wb3)
                : "v"(ia0), "v"(ia1), "v"(ia2), "v"(ia3), "v"(w));

            // ---- blob R: gate on row-n DMA, read slot j, drain ----
            float4 a0, a1, a2, a3;
            float  cr;
            {
                const unsigned ra = rowAddr + (unsigned)(j * 4352);
                const unsigned ca = cAddr   + (unsigned)(j * 4352);
                asm volatile(
                    "s_waitcnt vmcnt(35)\n\t"
                    "ds_read_b128 %0, %5 offset:0\n\t"
                    "ds_read_b128 %1, %5 offset:1024\n\t"
                    "ds_read_b128 %2, %5 offset:2048\n\t"
                    "ds_read_b128 %3, %5 offset:3072\n\t"
                    "ds_read_b32  %4, %6\n\t"
                    "s_waitcnt lgkmcnt(0)"
                    : "=&v"(a0), "=&v"(a1), "=&v"(a2), "=&v"(a3), "=&v"(cr)
                    : "v"(ra), "v"(ca));
            }

            // ---- store w_n (1 vm op) ----
            wo[n * 64] = w;

            // ---- DMA row n+8 -> slot j (5 vm ops; reads drained above) ----
            {
                int rowN = n + 8; if (rowN > L_ - 1) rowN = L_ - 1;
                const float* rp = Crow + (size_t)rowN * NC_;
                #pragma unroll
                for (int q = 0; q < 4; ++q)
                    dma16(rp + 256 * q + 4 * tid, &slots[j][256 * q]);
                dma4(cb + rowN * 32 + laneC, &slots[j][1024]);
            }

            // ---- matvec partials ----
            float p0, p1, p2, p3;
            p0 = fmaf(wb3, a0.w, fmaf(wb2, a0.z, fmaf(wb1, a0.y, wb0 * a0.x)));
            p1 = fmaf(wb3, a1.w, fmaf(wb2, a1.z, fmaf(wb1, a1.y, wb0 * a1.x)));
            p2 = fmaf(wb3, a2.w, fmaf(wb2, a2.z, fmaf(wb1, a2.y, wb0 * a2.x)));
            p3 = fmaf(wb3, a3.w, fmaf(wb2, a3.z, fmaf(wb1, a3.y, wb0 * a3.x)));

            p0 = octet_sum(p0);
            p1 = octet_sum(p1);
            p2 = octet_sum(p2);
            p3 = octet_sum(p3);

            // ---- blob D: redistribute from octet top lanes, drained ----
            float m0, m1, m2, m3;
            asm volatile(
                "ds_bpermute_b32 %0, %4, %5\n\t"
                "ds_bpermute_b32 %1, %4, %6\n\t"
                "ds_bpermute_b32 %2, %4, %7\n\t"
                "ds_bpermute_b32 %3, %4, %8\n\t"
                "s_waitcnt lgkmcnt(0)"
                : "=&v"(m0), "=&v"(m1), "=&v"(m2), "=&v"(m3)
                : "v"(idxRv), "v"(p0), "v"(p1), "v"(p2), "v"(p3));

            const float t0 = selA ? m1 : m0;
            const float t1 = selA ? m3 : m2;
            const float m  = selB ? t1 : t0;

            const float n2   = readlane_f(red, 31);
            const float rinv = rsqrtf(n2 + 1e-24f);
            w = fmaf(m, rinv, cr);
        }
    }
}

// ---------------------------------------------------------------------------
// Fused tail: left = w/||w|| + u; y1 = left.G + bb; out-proj; LN; gated res.
// ---------------------------------------------------------------------------
__global__ __launch_bounds__(256) void tail_kernel(
    const float* __restrict__ Cc, const float* __restrict__ x,
    const float* __restrict__ wBuf, const float* __restrict__ bb,
    const float* __restrict__ Wout, const float* __restrict__ bout,
    const float* __restrict__ gamma, const float* __restrict__ beta,
    float* __restrict__ out)
{
    __shared__ float lf[32];
    __shared__ float part[4][32];
    __shared__ float ys[32];
    __shared__ float red1[4], red2[4];

    const int bt = blockIdx.x;
    const int tid = threadIdx.x;

    if (tid < 64) {
        const float wv = wBuf[(size_t)bt * 64 + tid];
        float red = reduce32_to_lane31(wv * wv);
        const float n2 = readlane_f(red, 31);
        const float rn = rsqrtf(n2 + 1e-24f);
        if (tid < 32)
            lf[tid] = fmaf(wv, rn, x[(size_t)bt * D_ + tid]);  // left = h + u
    }
    __syncthreads();

    if (tid < 128) {
        const int j = tid & 31, q = tid >> 5;
        const float* Gp = Cc + (size_t)bt * NC_ + 1024;
        float p = 0.f;
        #pragma unroll
        for (int i = 0; i < 8; ++i)
            p = fmaf(lf[8 * q + i], Gp[(8 * q + i) * 32 + j], p);
        part[q][j] = p;
    }
    __syncthreads();
    if (tid < 32)
        ys[tid] = part[0][tid] + part[1][tid] + part[2][tid] + part[3][tid]
                + bb[tid];
    __syncthreads();

    float yv[2];
    #pragma unroll
    for (int q = 0; q < 2; ++q) {
        const int d = tid + q * 256;
        float acc = bout[d];
        #pragma unroll
        for (int j = 0; j < 32; ++j)
            acc = fmaf(ys[j], Wout[j * D_ + d], acc);
        yv[q] = acc;
    }

    float s1 = yv[0] + yv[1];
    float s2 = yv[0] * yv[0] + yv[1] * yv[1];
    #pragma unroll
    for (int m = 1; m <= 32; m <<= 1) {
        s1 += __shfl_xor(s1, m);
        s2 += __shfl_xor(s2, m);
    }
    const int wid = tid >> 6;
    if ((tid & 63) == 0) { red1[wid] = s1; red2[wid] = s2; }
    __syncthreads();
    const float S1 = red1[0] + red1[1] + red1[2] + red1[3];
    const float S2 = red2[0] + red2[1] + red2[2] + red2[3];
    const float mu  = S1 * (1.f / (float)D_);
    const float var = S2 * (1.f / (float)D_) - mu * mu;
    const float rstd = rsqrtf(var + 1e-6f);

    #pragma unroll
    for (int q = 0; q < 2; ++q) {
        const int d = tid + q * 256;
        const size_t gi = (size_t)bt * D_ + d;
        const float yn = (yv[q] - mu) * rstd * gamma[d] + beta[d];
        const float z = Cc[(size_t)bt * NC_ + 2048 + d];
        const float g = 1.f / (1.f + expf(-z));
        const float xv = x[gi];
        out[gi] = g * yn + (1.f - g) * xv;
    }
}

// ---------------------------------------------------------------------------
extern "C" void kernel_launch(void* const* d_in, const int* in_sizes, int n_in,
                              void* d_out, int out_size, void* d_ws, size_t ws_size,
                              hipStream_t stream)
{
    const float* x        = (const float*)d_in[0];
    const float* W_site   = (const float*)d_in[1];
    const float* b_site   = (const float*)d_in[2];
    const float* W_bridge = (const float*)d_in[3];
    const float* b_bridge = (const float*)d_in[4];
    const float* W_out    = (const float*)d_in[5];
    const float* b_out    = (const float*)d_in[6];
    const float* gamma    = (const float*)d_in[7];
    const float* beta     = (const float*)d_in[8];
    const float* W_gate   = (const float*)d_in[9];
    const float* b_gate   = (const float*)d_in[10];
    float* out = (float*)d_out;

    float* ws = (float*)d_ws;
    float* Wcomb = ws;                            //   512*2560
    float* biasC = Wcomb + (size_t)512 * NC_;
    float* Cc    = biasC + NC_;                   // 4096*2560 (42 MB)
    float* cBuf  = Cc    + (size_t)BT_ * NC_;
    float* wBuf  = cBuf  + (size_t)BT_ * 32;

    // 0. fold weights: [WA_perm | WW | W_gate] + fused bias
    buildW_kernel<<<dim3(513), dim3(256), 0, stream>>>(
        W_site, b_site, W_bridge, W_gate, b_gate, Wcomb, biasC);

    // 1. one fused GEMM: C = x @ Wcomb + biasC   [4096 x 2560, K=512]
    gemm_bias_kernel<<<dim3(NC_ / 64, BT_ / 64), dim3(256), 0, stream>>>(
        x, Wcomb, biasC, Cc, BT_, NC_, D_);

    // 2. c vectors: c = u . Abar  (fully parallel)
    cvec_kernel<<<dim3(BT_ / 4), dim3(256), 0, stream>>>(Cc, x, cBuf);

    // 3. serial scan (4 waves total) -> w_t
    scan_kernel<<<dim3(B_), dim3(64), 0, stream>>>(Cc, cBuf, wBuf);

    // 4. fused tail: bridge + out-proj + LN + gated residual
    tail_kernel<<<dim3(BT_), dim3(256), 0, stream>>>(
        Cc, x, wBuf, b_bridge, W_out, b_out, gamma, beta, out);
}